// Round 1
// 170.523 us; speedup vs baseline: 1.0377x; 1.0377x over previous
//
#include <hip/hip_runtime.h>

#define NA 4
#define NH 3
#define NHI 2
#define Bsz 32768
#define Ssz 256
#define Csz 16
#define Dsz 128
#define INsz 176
#define NP 20
#define KP 192
#define GT 2

typedef __bf16 v8bf __attribute__((ext_vector_type(8)));
typedef float v4f __attribute__((ext_vector_type(4)));

// ---- ws layout (bytes) ----
#define OFF_ENC    0                    // enc_t tiled: [B/16][16 subchunks][64 lanes][8] bf16 = 8388608
#define OFF_ACSBF  8388608              // NA*NH*Bsz*Csz*2    = 12582912
#define OFF_W1F    20971520             // NP*6*8*512*2       = 983040  (fragment-order)
#define OFF_ENCWF  21954560             // 8*8*512*2          = 65536   (fragment-order)
#define OFF_W2T    22020096             // NP*2048*2 bf16, layout [p][c][m][nt]
#define OFF_AMX    22102016             // NA*NH*Bsz          = 393216
#define OFF_ZERO   22495232             // 64 B zeros

// ---- prep ranges ----
#define N_ACSROW (NA*NH*Bsz)            // 393216
#define N_W1F   (NP*192*32)             // 122880
#define N_ENCWF (256*32)                // 8192
#define N_W2T   (NP*Csz*Dsz)            // 40960
#define N_ZERO  16
#define N_PREP  (N_ACSROW+N_W1F+N_ENCWF+N_W2T+N_ZERO)

__global__ __launch_bounds__(256) void prep_kernel(
    const float* __restrict__ acs, const float* __restrict__ encW,
    const float* __restrict__ eW1, const float* __restrict__ iW1,
    const float* __restrict__ eW2, const float* __restrict__ iW2,
    char* __restrict__ ws)
{
    long tid = (long)blockIdx.x * 256 + threadIdx.x;

    if (tid < N_ACSROW) {          // acs row: fp32->bf16 convert + first-max argmax, coalesced
        const float4* src = (const float4*)(acs + (size_t)tid * 16);
        float4 f0 = src[0], f1 = src[1], f2 = src[2], f3 = src[3];
        float v[16] = {f0.x,f0.y,f0.z,f0.w, f1.x,f1.y,f1.z,f1.w,
                       f2.x,f2.y,f2.z,f2.w, f3.x,f3.y,f3.z,f3.w};
        v8bf o0, o1;
        #pragma unroll
        for (int i = 0; i < 8; ++i) { o0[i] = (__bf16)v[i]; o1[i] = (__bf16)v[8 + i]; }
        v8bf* dst = (v8bf*)(ws + OFF_ACSBF) + tid * 2;
        dst[0] = o0; dst[1] = o1;
        float best = v[0]; int bi = 0;
        #pragma unroll
        for (int c = 1; c < 16; ++c) if (v[c] > best) { best = v[c]; bi = c; }
        ((unsigned char*)(ws + OFF_AMX))[tid] = (unsigned char)bi;
        return;
    }
    tid -= N_ACSROW;
    if (tid < N_W1F) {             // W1 -> bf16 fragment-order [p][kc][nt][lane][8]
        const int n4 = (int)(tid & 31) * 4;
        const int k  = (int)((tid >> 5) % 192);
        const int p  = (int)(tid / 6144);
        const float* W1;
        if (p < 12) { int ai = p / 3, hj = p % 3; W1 = eW1 + (size_t)(hj * NA + ai) * INsz * Dsz; }
        else { int qq = p - 12; int ai = qq >> 1, jj = qq & 1; W1 = iW1 + (size_t)(jj * NA + ai) * INsz * Dsz; }
        float4 f = (k < INsz) ? *(const float4*)(W1 + (size_t)k * Dsz + n4)
                              : (float4){0.f, 0.f, 0.f, 0.f};
        const int kc = k >> 5, q = (k >> 3) & 3, j = k & 7;
        __bf16* dst = (__bf16*)(ws + OFF_W1F);
        const float fv[4] = {f.x, f.y, f.z, f.w};
        #pragma unroll
        for (int i = 0; i < 4; ++i) {
            const int n = n4 + i, nt = n >> 4, m = n & 15;
            dst[((size_t)(p * 6 + kc) * 8 + nt) * 512 + (q * 16 + m) * 8 + j] = (__bf16)fv[i];
        }
        return;
    }
    tid -= N_W1F;
    if (tid < N_ENCWF) {           // encW -> bf16 fragment-order [kc][nt][lane][8]
        const int n4 = (int)(tid & 31) * 4;
        const int k  = (int)(tid >> 5);
        float4 f = *(const float4*)(encW + (size_t)k * Dsz + n4);
        const int kc = k >> 5, q = (k >> 3) & 3, j = k & 7;
        __bf16* dst = (__bf16*)(ws + OFF_ENCWF);
        const float fv[4] = {f.x, f.y, f.z, f.w};
        #pragma unroll
        for (int i = 0; i < 4; ++i) {
            const int n = n4 + i, nt = n >> 4, m = n & 15;
            dst[((size_t)kc * 8 + nt) * 512 + (q * 16 + m) * 8 + j] = (__bf16)fv[i];
        }
        return;
    }
    tid -= N_ENCWF;
    if (tid < N_W2T) {             // W2 -> bf16 [p][c][m][nt]  (d = nt*16 + m)
        int d = (int)(tid & 127);
        int rest = (int)(tid >> 7);
        int c = rest & 15, p = rest >> 4;
        const float* W2;
        if (p < 12) { int ai = p / 3, hj = p % 3; W2 = eW2 + (size_t)(hj * NA + ai) * Dsz * Csz; }
        else { int qq = p - 12; int ai = qq >> 1, jj = qq & 1; W2 = iW2 + (size_t)(jj * NA + ai) * Dsz * Csz; }
        ((__bf16*)(ws + OFF_W2T))[(size_t)p * 2048 + c * 128 + (d & 15) * 8 + (d >> 4)]
            = (__bf16)W2[(size_t)d * Csz + c];
        return;
    }
    tid -= N_W2T;
    if (tid < N_ZERO) ((float*)(ws + OFF_ZERO))[tid] = 0.f;
}

// ---------------- encoder: MFMA as before; epilogue via per-wave LDS transpose ----------------
// Output layout enc_t: byte = rt*4096 + s*256 + m*16 + j*2  holds enc[rt*16 + m][s*8 + j]
// (s = 0..15 sub-chunk of 8 cols; matches critic A-fragment read exactly -> 1KB contiguous/wave)
__global__ __launch_bounds__(256) void enc_kernel(const float* __restrict__ sv,
                                                  const float* __restrict__ encb,
                                                  char* __restrict__ ws)
{
    __shared__ __bf16 tb[4][16 * 136];   // per-wave 16 rows x 136 (pad for banks+align)

    const int t = threadIdx.x;
    const int wv = t >> 6, lane = t & 63, m = lane & 15, q = lane >> 4;
    const int R = blockIdx.x * 64 + wv * 16 + m;
    const __bf16* encwf = (const __bf16*)(ws + OFF_ENCWF);
    char* enct = ws + OFF_ENC;

    v4f acc[8];
    #pragma unroll
    for (int nt = 0; nt < 8; ++nt) acc[nt] = (v4f){0.f, 0.f, 0.f, 0.f};

    const float* arow = sv + (size_t)R * Ssz + q * 8;
    #pragma unroll
    for (int kc = 0; kc < 8; ++kc) {
        float4 f0 = *(const float4*)(arow + kc * 32);
        float4 f1 = *(const float4*)(arow + kc * 32 + 4);
        v8bf af;
        af[0]=(__bf16)f0.x; af[1]=(__bf16)f0.y; af[2]=(__bf16)f0.z; af[3]=(__bf16)f0.w;
        af[4]=(__bf16)f1.x; af[5]=(__bf16)f1.y; af[6]=(__bf16)f1.z; af[7]=(__bf16)f1.w;
        #pragma unroll
        for (int nt = 0; nt < 8; ++nt) {
            v8bf bf = *(const v8bf*)(encwf + ((size_t)kc * 8 + nt) * 512 + lane * 8);
            acc[nt] = __builtin_amdgcn_mfma_f32_16x16x32_bf16(af, bf, acc[nt], 0, 0, 0);
        }
    }
    // bias+relu, write transposed into per-wave LDS tile (row = q*4+rg, col = nt*16+m)
    #pragma unroll
    for (int nt = 0; nt < 8; ++nt) {
        const float bias = encb[nt * 16 + m];
        #pragma unroll
        for (int rg = 0; rg < 4; ++rg) {
            float v = acc[nt][rg] + bias;
            v = v > 0.f ? v : 0.f;
            tb[wv][(q * 4 + rg) * 136 + nt * 16 + m] = (__bf16)v;
        }
    }
    __syncthreads();
    // read back in A-fragment order (row = m, cols kc*32 + q*8 ..+8) and store coalesced
    const int rt = blockIdx.x * 4 + wv;
    #pragma unroll
    for (int kc = 0; kc < 4; ++kc) {
        v8bf v = *(const v8bf*)&tb[wv][m * 136 + kc * 32 + q * 8];
        *(v8bf*)(enct + ((size_t)(rt * 4 + kc) * 64 + lane) * 16) = v;
    }
}

// ---------------- critic: mt=4 (64 rows/wave), G=2 tiles/block, af double-buffer, LDS w2 ----------------
#define LD_AF(D, KC, GG) \
  { _Pragma("unroll") \
    for (int mt_ = 0; mt_ < 4; ++mt_) \
      D[mt_] = *(const v8bf*)(base[KC] + (size_t)((mt_ + 16 * (GG)) * strd[KC])); }

#define MFMA_KC(AF, KC) \
  { _Pragma("unroll") \
    for (int nt_ = 0; nt_ < 8; ++nt_) { \
      v8bf bf_ = *(const v8bf*)&w1s[(size_t)(((KC) * 8 + nt_) * 512) + lane * 8]; \
      acc[0][nt_] = __builtin_amdgcn_mfma_f32_16x16x32_bf16(AF[0], bf_, acc[0][nt_], 0, 0, 0); \
      acc[1][nt_] = __builtin_amdgcn_mfma_f32_16x16x32_bf16(AF[1], bf_, acc[1][nt_], 0, 0, 0); \
      acc[2][nt_] = __builtin_amdgcn_mfma_f32_16x16x32_bf16(AF[2], bf_, acc[2][nt_], 0, 0, 0); \
      acc[3][nt_] = __builtin_amdgcn_mfma_f32_16x16x32_bf16(AF[3], bf_, acc[3][nt_], 0, 0, 0); \
    } }

__global__ __launch_bounds__(256, 2) void critic_kernel(
    const float* __restrict__ eb1, const float* __restrict__ eb2,
    const float* __restrict__ ib1, const float* __restrict__ ib2,
    const char* __restrict__ ws, float* __restrict__ out)
{
    __shared__ __bf16 w1s[6 * 8 * 512];   // 48 KB B-panel, fragment order
    __shared__ __bf16 w2s[16 * 136];      // 4.25 KB W2 [c][m][nt], padded stride

    const int t = threadIdx.x;
    const int p  = blockIdx.y;
    const int rb = blockIdx.x;
    const int wv = t >> 6, lane = t & 63, m = lane & 15, q = lane >> 4;

    int ai, hj;
    const float *b1, *b2;
    float* outp;
    if (p < 12) {
        ai = p / 3; hj = p % 3;
        const int wi = hj * NA + ai;
        b1 = eb1 + (size_t)wi * Dsz; b2 = eb2 + (size_t)wi * Csz;
        outp = out + (size_t)(ai * NH + hj) * Bsz;
    } else {
        const int qq = p - 12; ai = qq >> 1; const int jj = qq & 1; hj = jj + 1;
        const int wi = jj * NA + ai;
        b1 = ib1 + (size_t)wi * Dsz; b2 = ib2 + (size_t)wi * Csz;
        outp = out + (size_t)NA * NH * Bsz + (size_t)(ai * NHI + jj) * Bsz;
    }

    const char* acsb = ws + OFF_ACSBF;
    const char* enct = ws + OFF_ENC;
    const __bf16* w1f = (const __bf16*)(ws + OFF_W1F) + (size_t)p * 6 * 8 * 512;
    const __bf16* w2t = (const __bf16*)(ws + OFF_W2T) + (size_t)p * 2048;
    const unsigned char* amxp = (const unsigned char*)(ws + OFF_AMX)
        + (size_t)(ai * NH + hj) * Bsz + (size_t)rb * 512 + wv * 64;
    const char* zerop = ws + OFF_ZERO;

    // stage B panel (48 KB) + W2 (4 KB) into LDS
    {
        const v8bf* src = (const v8bf*)w1f;
        #pragma unroll
        for (int i = 0; i < 12; ++i)
            ((v8bf*)w1s)[i * 256 + t] = src[i * 256 + t];
        v8bf wv2 = ((const v8bf*)w2t)[t];
        *(v8bf*)&w2s[(t >> 4) * 136 + (t & 15) * 8] = wv2;
    }

    // per-lane A-fragment base pointers; stride = bytes per 16-row (mt) step
    const int loo0 = 0 + (0 >= ai), loo1 = 1 + (1 >= ai), loo2 = 2 + (2 >= ai);
    const size_t rowoff = ((size_t)rb * 512 + wv * 64 + m) * 32;
    const char* pl0 = acsb + (size_t)(loo0 * NH + hj) * Bsz * 32 + rowoff;
    const char* pl1 = acsb + (size_t)(loo1 * NH + hj) * Bsz * 32 + rowoff;
    const char* pl2 = acsb + (size_t)(loo2 * NH + hj) * Bsz * 32 + rowoff;
    const int rt0 = rb * 32 + wv * 4;
    const char* encB = enct + (size_t)rt0 * 4096 + m * 16;

    const char* base[6];
    int strd[6];
    base[0] = (q < 2) ? (pl0 + q * 16) : (pl1 + (q - 2) * 16);           strd[0] = 512;
    base[1] = (q < 2) ? (pl2 + q * 16) : (encB + (q - 2) * 256);         strd[1] = (q < 2) ? 512 : 4096;
    base[2] = encB + (q + 2)  * 256;                                     strd[2] = 4096;
    base[3] = encB + (q + 6)  * 256;                                     strd[3] = 4096;
    base[4] = encB + (q + 10) * 256;                                     strd[4] = 4096;
    base[5] = (q < 2) ? (encB + (14 + q) * 256) : zerop;                 strd[5] = (q < 2) ? 4096 : 0;

    float b1v[8];
    #pragma unroll
    for (int nt = 0; nt < 8; ++nt) b1v[nt] = b1[nt * 16 + m];

    v4f acc[4][8];
    #pragma unroll
    for (int i = 0; i < 4; ++i)
        #pragma unroll
        for (int j = 0; j < 8; ++j)
            acc[i][j] = (v4f){0.f, 0.f, 0.f, 0.f};

    v8bf afA[4], afB[4];
    LD_AF(afA, 0, 0)            // prefetch first A-fragments before the barrier

    __syncthreads();

    #pragma unroll
    for (int g = 0; g < GT; ++g) {
        unsigned int cw[4];
        #pragma unroll
        for (int mt = 0; mt < 4; ++mt)
            cw[mt] = *(const unsigned int*)(amxp + g * 256 + mt * 16 + q * 4);

        LD_AF(afB, 1, g)  MFMA_KC(afA, 0)
        LD_AF(afA, 2, g)  MFMA_KC(afB, 1)
        LD_AF(afB, 3, g)  MFMA_KC(afA, 2)
        LD_AF(afA, 4, g)  MFMA_KC(afB, 3)
        LD_AF(afB, 5, g)  MFMA_KC(afA, 4)
        if (g + 1 < GT) { LD_AF(afA, 0, g + 1) }
        MFMA_KC(afB, 5)

        // epilogue: relu(acc+b1) . w2[:,argmax] from LDS, shfl over the 16 m-lanes
        #pragma unroll
        for (int mt = 0; mt < 4; ++mt) {
            const unsigned int cwv = cw[mt];
            #pragma unroll
            for (int rg = 0; rg < 4; ++rg) {
                const int c = (cwv >> (8 * rg)) & 255;
                const v8bf w2v = *(const v8bf*)&w2s[c * 136 + m * 8];
                float partial = 0.f;
                #pragma unroll
                for (int nt = 0; nt < 8; ++nt) {
                    float h = acc[mt][nt][rg] + b1v[nt];
                    h = h > 0.f ? h : 0.f;
                    partial += h * (float)w2v[nt];
                }
                partial += __shfl_xor(partial, 1, 64);
                partial += __shfl_xor(partial, 2, 64);
                partial += __shfl_xor(partial, 4, 64);
                partial += __shfl_xor(partial, 8, 64);
                if (m == 0)
                    outp[(size_t)rb * 512 + g * 256 + wv * 64 + mt * 16 + q * 4 + rg]
                        = partial + b2[c];
            }
            if (g + 1 < GT) {
                #pragma unroll
                for (int nt = 0; nt < 8; ++nt) acc[mt][nt] = (v4f){0.f, 0.f, 0.f, 0.f};
            }
        }
    }
}

extern "C" void kernel_launch(void* const* d_in, const int* in_sizes, int n_in,
                              void* d_out, int out_size, void* d_ws, size_t ws_size,
                              hipStream_t stream) {
    const float* sv   = (const float*)d_in[0];
    const float* acs  = (const float*)d_in[1];
    const float* encW = (const float*)d_in[2];
    const float* encb = (const float*)d_in[3];
    const float* eW1  = (const float*)d_in[4];
    const float* eb1  = (const float*)d_in[5];
    const float* eW2  = (const float*)d_in[6];
    const float* eb2  = (const float*)d_in[7];
    const float* iW1  = (const float*)d_in[8];
    const float* ib1  = (const float*)d_in[9];
    const float* iW2  = (const float*)d_in[10];
    const float* ib2  = (const float*)d_in[11];
    float* out = (float*)d_out;
    char* ws = (char*)d_ws;

    hipLaunchKernelGGL(prep_kernel, dim3((N_PREP + 255) / 256), dim3(256), 0, stream,
                       acs, encW, eW1, iW1, eW2, iW2, ws);
    hipLaunchKernelGGL(enc_kernel, dim3(Bsz / 64), dim3(256), 0, stream, sv, encb, ws);
    hipLaunchKernelGGL(critic_kernel, dim3(Bsz / 512, NP), dim3(256), 0, stream,
                       eb1, eb2, ib1, ib2, ws, out);
}

// Round 2
// 162.585 us; speedup vs baseline: 1.0883x; 1.0488x over previous
//
#include <hip/hip_runtime.h>

#define NA 4
#define NH 3
#define NHI 2
#define Bsz 32768
#define Ssz 256
#define Csz 16
#define Dsz 128
#define INsz 176
#define NP 20
#define KP 192
#define GT 2

typedef __bf16 v8bf __attribute__((ext_vector_type(8)));
typedef float v4f __attribute__((ext_vector_type(4)));

// ---- ws layout (bytes) ----
#define OFF_ENC    0                    // enc_t tiled: [B/16][16 subchunks][64 lanes][8] bf16 = 8388608
#define OFF_ACSBF  8388608              // NA*NH*Bsz*Csz*2    = 12582912
#define OFF_W1F    20971520             // NP*6*8*512*2       = 983040  (fragment-order, k=176 row = b1)
#define OFF_ENCWF  21954560             // 8*8*512*2          = 65536   (fragment-order)
#define OFF_W2T    22020096             // NP*2048*2 bf16, layout [p][c][(dlow^c)][dtile]
#define OFF_AMX    22102016             // NA*NH*Bsz          = 393216
#define OFF_ZERO   22495232             // 64 B: bf16 {1.0, 0...} then zeros (one-hot bias row)

// ---- prep ranges ----
#define N_ACSROW (NA*NH*Bsz)            // 393216
#define N_W1F   (NP*192*32)             // 122880
#define N_ENCWF (256*32)                // 8192
#define N_W2T   (NP*Csz*Dsz)            // 40960
#define N_ZERO  16
#define N_PREP  (N_ACSROW+N_W1F+N_ENCWF+N_W2T+N_ZERO)

__global__ __launch_bounds__(256) void prep_kernel(
    const float* __restrict__ acs, const float* __restrict__ encW,
    const float* __restrict__ eW1, const float* __restrict__ iW1,
    const float* __restrict__ eW2, const float* __restrict__ iW2,
    const float* __restrict__ eb1, const float* __restrict__ ib1,
    char* __restrict__ ws)
{
    long tid = (long)blockIdx.x * 256 + threadIdx.x;

    if (tid < N_ACSROW) {          // acs row: fp32->bf16 convert + first-max argmax, coalesced
        const float4* src = (const float4*)(acs + (size_t)tid * 16);
        float4 f0 = src[0], f1 = src[1], f2 = src[2], f3 = src[3];
        float v[16] = {f0.x,f0.y,f0.z,f0.w, f1.x,f1.y,f1.z,f1.w,
                       f2.x,f2.y,f2.z,f2.w, f3.x,f3.y,f3.z,f3.w};
        v8bf o0, o1;
        #pragma unroll
        for (int i = 0; i < 8; ++i) { o0[i] = (__bf16)v[i]; o1[i] = (__bf16)v[8 + i]; }
        v8bf* dst = (v8bf*)(ws + OFF_ACSBF) + tid * 2;
        dst[0] = o0; dst[1] = o1;
        float best = v[0]; int bi = 0;
        #pragma unroll
        for (int c = 1; c < 16; ++c) if (v[c] > best) { best = v[c]; bi = c; }
        ((unsigned char*)(ws + OFF_AMX))[tid] = (unsigned char)bi;
        return;
    }
    tid -= N_ACSROW;
    if (tid < N_W1F) {             // W1 -> bf16 fragment-order [p][kc][nt][lane][8]; k==176 row = b1
        const int n4 = (int)(tid & 31) * 4;
        const int k  = (int)((tid >> 5) % 192);
        const int p  = (int)(tid / 6144);
        const float* W1; const float* B1;
        if (p < 12) { int ai = p / 3, hj = p % 3; int wi = hj * NA + ai;
                      W1 = eW1 + (size_t)wi * INsz * Dsz; B1 = eb1 + (size_t)wi * Dsz; }
        else { int qq = p - 12; int ai = qq >> 1, jj = qq & 1; int wi = jj * NA + ai;
               W1 = iW1 + (size_t)wi * INsz * Dsz; B1 = ib1 + (size_t)wi * Dsz; }
        float4 f;
        if (k < INsz)       f = *(const float4*)(W1 + (size_t)k * Dsz + n4);
        else if (k == INsz) f = *(const float4*)(B1 + n4);
        else                f = (float4){0.f, 0.f, 0.f, 0.f};
        const int kc = k >> 5, q = (k >> 3) & 3, j = k & 7;
        __bf16* dst = (__bf16*)(ws + OFF_W1F);
        const float fv[4] = {f.x, f.y, f.z, f.w};
        #pragma unroll
        for (int i = 0; i < 4; ++i) {
            const int n = n4 + i, nt = n >> 4, m = n & 15;
            dst[((size_t)(p * 6 + kc) * 8 + nt) * 512 + (q * 16 + m) * 8 + j] = (__bf16)fv[i];
        }
        return;
    }
    tid -= N_W1F;
    if (tid < N_ENCWF) {           // encW -> bf16 fragment-order [kc][nt][lane][8]
        const int n4 = (int)(tid & 31) * 4;
        const int k  = (int)(tid >> 5);
        float4 f = *(const float4*)(encW + (size_t)k * Dsz + n4);
        const int kc = k >> 5, q = (k >> 3) & 3, j = k & 7;
        __bf16* dst = (__bf16*)(ws + OFF_ENCWF);
        const float fv[4] = {f.x, f.y, f.z, f.w};
        #pragma unroll
        for (int i = 0; i < 4; ++i) {
            const int n = n4 + i, nt = n >> 4, m = n & 15;
            dst[((size_t)kc * 8 + nt) * 512 + (q * 16 + m) * 8 + j] = (__bf16)fv[i];
        }
        return;
    }
    tid -= N_ENCWF;
    if (tid < N_W2T) {             // W2 -> bf16 [p][c][(dlow^c)][dtile]  (d = dtile*16 + dlow)
        int d = (int)(tid & 127);
        int rest = (int)(tid >> 7);
        int c = rest & 15, p = rest >> 4;
        const float* W2;
        if (p < 12) { int ai = p / 3, hj = p % 3; W2 = eW2 + (size_t)(hj * NA + ai) * Dsz * Csz; }
        else { int qq = p - 12; int ai = qq >> 1, jj = qq & 1; W2 = iW2 + (size_t)(jj * NA + ai) * Dsz * Csz; }
        const int dlow = d & 15, dt = d >> 4;
        ((__bf16*)(ws + OFF_W2T))[(size_t)p * 2048 + c * 128 + ((dlow ^ c) * 8) + dt]
            = (__bf16)W2[(size_t)d * Csz + c];
        return;
    }
    tid -= N_W2T;
    if (tid < N_ZERO) {            // one-hot bias-row feed: bf16 {1.0, 0,0,...} then zeros
        ((unsigned int*)(ws + OFF_ZERO))[tid] = (tid == 0) ? 0x00003F80u : 0u;
    }
}

// ---------------- encoder: MFMA; epilogue via per-wave LDS transpose ----------------
// Output layout enc_t: byte = rt*4096 + s*256 + m*16 + j*2  holds enc[rt*16 + m][s*8 + j]
__global__ __launch_bounds__(256) void enc_kernel(const float* __restrict__ sv,
                                                  const float* __restrict__ encb,
                                                  char* __restrict__ ws)
{
    __shared__ __bf16 tb[4][16 * 136];   // per-wave 16 rows x 136 (pad for banks+align)

    const int t = threadIdx.x;
    const int wv = t >> 6, lane = t & 63, m = lane & 15, q = lane >> 4;
    const int R = blockIdx.x * 64 + wv * 16 + m;
    const __bf16* encwf = (const __bf16*)(ws + OFF_ENCWF);
    char* enct = ws + OFF_ENC;

    v4f acc[8];
    #pragma unroll
    for (int nt = 0; nt < 8; ++nt) acc[nt] = (v4f){0.f, 0.f, 0.f, 0.f};

    const float* arow = sv + (size_t)R * Ssz + q * 8;
    #pragma unroll
    for (int kc = 0; kc < 8; ++kc) {
        float4 f0 = *(const float4*)(arow + kc * 32);
        float4 f1 = *(const float4*)(arow + kc * 32 + 4);
        v8bf af;
        af[0]=(__bf16)f0.x; af[1]=(__bf16)f0.y; af[2]=(__bf16)f0.z; af[3]=(__bf16)f0.w;
        af[4]=(__bf16)f1.x; af[5]=(__bf16)f1.y; af[6]=(__bf16)f1.z; af[7]=(__bf16)f1.w;
        #pragma unroll
        for (int nt = 0; nt < 8; ++nt) {
            v8bf bf = *(const v8bf*)(encwf + ((size_t)kc * 8 + nt) * 512 + lane * 8);
            acc[nt] = __builtin_amdgcn_mfma_f32_16x16x32_bf16(af, bf, acc[nt], 0, 0, 0);
        }
    }
    #pragma unroll
    for (int nt = 0; nt < 8; ++nt) {
        const float bias = encb[nt * 16 + m];
        #pragma unroll
        for (int rg = 0; rg < 4; ++rg) {
            float v = acc[nt][rg] + bias;
            v = v > 0.f ? v : 0.f;
            tb[wv][(q * 4 + rg) * 136 + nt * 16 + m] = (__bf16)v;
        }
    }
    __syncthreads();
    const int rt = blockIdx.x * 4 + wv;
    #pragma unroll
    for (int kc = 0; kc < 4; ++kc) {
        v8bf v = *(const v8bf*)&tb[wv][m * 136 + kc * 32 + q * 8];
        *(v8bf*)(enct + ((size_t)(rt * 4 + kc) * 64 + lane) * 16) = v;
    }
}

// ---------------- critic: SWAPPED mfma (D[d_low, row]) -> lane-local W2 reduce ----------------
#define LD_AF(D, KC, GG) \
  { _Pragma("unroll") \
    for (int mt_ = 0; mt_ < 4; ++mt_) \
      D[mt_] = *(const v8bf*)(base[KC] + (size_t)((mt_ + 16 * (GG)) * strd[KC])); }

// swapped operand order: A = W1 fragment (from LDS), B = X fragment (per-lane rows)
#define MFMA_KC(AF, KC) \
  { _Pragma("unroll") \
    for (int nt_ = 0; nt_ < 8; ++nt_) { \
      v8bf bf_ = *(const v8bf*)&w1s[(size_t)(((KC) * 8 + nt_) * 512) + lane * 8]; \
      acc[0][nt_] = __builtin_amdgcn_mfma_f32_16x16x32_bf16(bf_, AF[0], acc[0][nt_], 0, 0, 0); \
      acc[1][nt_] = __builtin_amdgcn_mfma_f32_16x16x32_bf16(bf_, AF[1], acc[1][nt_], 0, 0, 0); \
      acc[2][nt_] = __builtin_amdgcn_mfma_f32_16x16x32_bf16(bf_, AF[2], acc[2][nt_], 0, 0, 0); \
      acc[3][nt_] = __builtin_amdgcn_mfma_f32_16x16x32_bf16(bf_, AF[3], acc[3][nt_], 0, 0, 0); \
    } }

__global__ __launch_bounds__(256, 2) void critic_kernel(
    const float* __restrict__ eb2, const float* __restrict__ ib2,
    const char* __restrict__ ws, float* __restrict__ out)
{
    __shared__ __bf16 w1s[6 * 8 * 512];   // 48 KB B-panel (incl. bias row k=176), fragment order
    __shared__ __bf16 w2s[16 * 128];      // 4 KB W2 [c][(dlow^c)][dtile]

    const int t = threadIdx.x;
    const int p  = blockIdx.y;
    const int rb = blockIdx.x;
    const int wv = t >> 6, lane = t & 63, m = lane & 15, q = lane >> 4;

    int ai, hj;
    const float* b2;
    float* outp;
    if (p < 12) {
        ai = p / 3; hj = p % 3;
        b2 = eb2 + (size_t)(hj * NA + ai) * Csz;
        outp = out + (size_t)(ai * NH + hj) * Bsz;
    } else {
        const int qq = p - 12; ai = qq >> 1; const int jj = qq & 1; hj = jj + 1;
        b2 = ib2 + (size_t)(jj * NA + ai) * Csz;
        outp = out + (size_t)NA * NH * Bsz + (size_t)(ai * NHI + jj) * Bsz;
    }

    const char* acsb = ws + OFF_ACSBF;
    const char* enct = ws + OFF_ENC;
    const __bf16* w1f = (const __bf16*)(ws + OFF_W1F) + (size_t)p * 6 * 8 * 512;
    const __bf16* w2t = (const __bf16*)(ws + OFF_W2T) + (size_t)p * 2048;
    const unsigned char* amxp = (const unsigned char*)(ws + OFF_AMX)
        + (size_t)(ai * NH + hj) * Bsz + (size_t)rb * 512 + wv * 64;
    const char* zerop = ws + OFF_ZERO;

    // stage W1 panel (48 KB) + W2 (4 KB) into LDS (layouts already baked, linear copies)
    {
        const v8bf* src = (const v8bf*)w1f;
        #pragma unroll
        for (int i = 0; i < 12; ++i)
            ((v8bf*)w1s)[i * 256 + t] = src[i * 256 + t];
        ((v8bf*)w2s)[t] = ((const v8bf*)w2t)[t];
    }

    // per-lane X-fragment base pointers; stride = bytes per 16-row (mt) step
    const int loo0 = 0 + (0 >= ai), loo1 = 1 + (1 >= ai), loo2 = 2 + (2 >= ai);
    const size_t rowoff = ((size_t)rb * 512 + wv * 64 + m) * 32;
    const char* pl0 = acsb + (size_t)(loo0 * NH + hj) * Bsz * 32 + rowoff;
    const char* pl1 = acsb + (size_t)(loo1 * NH + hj) * Bsz * 32 + rowoff;
    const char* pl2 = acsb + (size_t)(loo2 * NH + hj) * Bsz * 32 + rowoff;
    const int rt0 = rb * 32 + wv * 4;
    const char* encB = enct + (size_t)rt0 * 4096 + m * 16;

    const char* base[6];
    int strd[6];
    base[0] = (q < 2) ? (pl0 + q * 16) : (pl1 + (q - 2) * 16);           strd[0] = 512;
    base[1] = (q < 2) ? (pl2 + q * 16) : (encB + (q - 2) * 256);         strd[1] = (q < 2) ? 512 : 4096;
    base[2] = encB + (q + 2)  * 256;                                     strd[2] = 4096;
    base[3] = encB + (q + 6)  * 256;                                     strd[3] = 4096;
    base[4] = encB + (q + 10) * 256;                                     strd[4] = 4096;
    base[5] = (q < 2) ? (encB + (14 + q) * 256) : (zerop + (q - 2) * 16);
    strd[5] = (q < 2) ? 4096 : 0;    // q==2 reads {1,0,..} -> bias row; q==3 reads zeros

    v4f acc[4][8];
    #pragma unroll
    for (int i = 0; i < 4; ++i)
        #pragma unroll
        for (int j = 0; j < 8; ++j)
            acc[i][j] = (v4f){0.f, 0.f, 0.f, 0.f};

    v8bf afA[4], afB[4];
    LD_AF(afA, 0, 0)            // prefetch first X-fragments before the barrier

    __syncthreads();

    #pragma unroll
    for (int g = 0; g < GT; ++g) {
        // prefetch this g's argmax bytes (needed only at epilogue)
        int cb[4];
        #pragma unroll
        for (int mt = 0; mt < 4; ++mt)
            cb[mt] = amxp[g * 256 + mt * 16 + m];

        LD_AF(afB, 1, g)  MFMA_KC(afA, 0)
        LD_AF(afA, 2, g)  MFMA_KC(afB, 1)
        LD_AF(afB, 3, g)  MFMA_KC(afA, 2)
        LD_AF(afA, 4, g)  MFMA_KC(afB, 3)
        LD_AF(afB, 5, g)  MFMA_KC(afA, 4)
        if (g + 1 < GT) { LD_AF(afA, 0, g + 1) }
        MFMA_KC(afB, 5)

        // epilogue: lane holds z[d = nt*16 + q*4 + rg] of row (mt*16 + m); bias already folded.
        // sum_d relu(z)*w2[d, c_row] = 32 in-lane fma + 2 shfl.
        #pragma unroll
        for (int mt = 0; mt < 4; ++mt) {
            const int c = cb[mt];
            const v8bf wv0 = *(const v8bf*)&w2s[c * 128 + ((q * 4 + 0) ^ c) * 8];
            const v8bf wv1 = *(const v8bf*)&w2s[c * 128 + ((q * 4 + 1) ^ c) * 8];
            const v8bf wv2 = *(const v8bf*)&w2s[c * 128 + ((q * 4 + 2) ^ c) * 8];
            const v8bf wv3 = *(const v8bf*)&w2s[c * 128 + ((q * 4 + 3) ^ c) * 8];
            float s0 = 0.f, s1 = 0.f, s2 = 0.f, s3 = 0.f;
            #pragma unroll
            for (int nt = 0; nt < 8; ++nt) {
                const v4f z = acc[mt][nt];
                s0 += fmaxf(z[0], 0.f) * (float)wv0[nt];
                s1 += fmaxf(z[1], 0.f) * (float)wv1[nt];
                s2 += fmaxf(z[2], 0.f) * (float)wv2[nt];
                s3 += fmaxf(z[3], 0.f) * (float)wv3[nt];
            }
            float tsum = (s0 + s1) + (s2 + s3);
            tsum += __shfl_xor(tsum, 16, 64);
            tsum += __shfl_xor(tsum, 32, 64);
            if (q == 0)
                outp[(size_t)rb * 512 + g * 256 + wv * 64 + mt * 16 + m] = tsum + b2[c];
            if (g + 1 < GT) {
                #pragma unroll
                for (int nt = 0; nt < 8; ++nt) acc[mt][nt] = (v4f){0.f, 0.f, 0.f, 0.f};
            }
        }
    }
}

extern "C" void kernel_launch(void* const* d_in, const int* in_sizes, int n_in,
                              void* d_out, int out_size, void* d_ws, size_t ws_size,
                              hipStream_t stream) {
    const float* sv   = (const float*)d_in[0];
    const float* acs  = (const float*)d_in[1];
    const float* encW = (const float*)d_in[2];
    const float* encb = (const float*)d_in[3];
    const float* eW1  = (const float*)d_in[4];
    const float* eb1  = (const float*)d_in[5];
    const float* eW2  = (const float*)d_in[6];
    const float* eb2  = (const float*)d_in[7];
    const float* iW1  = (const float*)d_in[8];
    const float* ib1  = (const float*)d_in[9];
    const float* iW2  = (const float*)d_in[10];
    const float* ib2  = (const float*)d_in[11];
    float* out = (float*)d_out;
    char* ws = (char*)d_ws;

    hipLaunchKernelGGL(prep_kernel, dim3((N_PREP + 255) / 256), dim3(256), 0, stream,
                       acs, encW, eW1, iW1, eW2, iW2, eb1, ib1, ws);
    hipLaunchKernelGGL(enc_kernel, dim3(Bsz / 64), dim3(256), 0, stream, sv, encb, ws);
    hipLaunchKernelGGL(critic_kernel, dim3(Bsz / 512, NP), dim3(256), 0, stream,
                       eb2, ib2, ws, out);
}

// Round 3
// 162.025 us; speedup vs baseline: 1.0921x; 1.0035x over previous
//
#include <hip/hip_runtime.h>

#define NA 4
#define NH 3
#define NHI 2
#define Bsz 32768
#define Ssz 256
#define Csz 16
#define Dsz 128
#define INsz 176
#define NP 20
#define KP 192
#define GT 2

typedef __bf16 v8bf __attribute__((ext_vector_type(8)));
typedef float v4f __attribute__((ext_vector_type(4)));

// ---- ws layout (bytes) ----
#define OFF_ENC    0                    // enc_t tiled: [B/16][16 subchunks][64 lanes][8] bf16 = 8388608
#define OFF_ACSBF  8388608              // NA*NH*Bsz*Csz*2    = 12582912
#define OFF_W1F    20971520             // NP*6*8*512*2       = 983040  (fragment-order, k=176 row = b1)
#define OFF_ENCWF  21954560             // 8*8*512*2          = 65536   (fragment-order)
#define OFF_W2T    22020096             // NP*2048*2 bf16, layout [p][c][(dlow^c)][dtile]
#define OFF_AMX    22102016             // NA*NH*Bsz          = 393216
#define OFF_ZERO   22495232             // 64 B: bf16 {1.0, 0...} then zeros (one-hot bias row)

// ---- prep ranges ----
#define N_ACSROW (NA*NH*Bsz)            // 393216
#define N_W1F   (NP*192*32)             // 122880
#define N_ENCWF (256*32)                // 8192
#define N_W2T   (NP*Csz*Dsz)            // 40960
#define N_ZERO  16
#define N_PREP  (N_ACSROW+N_W1F+N_ENCWF+N_W2T+N_ZERO)

__global__ __launch_bounds__(256) void prep_kernel(
    const float* __restrict__ acs, const float* __restrict__ encW,
    const float* __restrict__ eW1, const float* __restrict__ iW1,
    const float* __restrict__ eW2, const float* __restrict__ iW2,
    const float* __restrict__ eb1, const float* __restrict__ ib1,
    char* __restrict__ ws)
{
    long tid = (long)blockIdx.x * 256 + threadIdx.x;

    if (tid < N_ACSROW) {          // acs row: fp32->bf16 convert + first-max argmax, coalesced
        const float4* src = (const float4*)(acs + (size_t)tid * 16);
        float4 f0 = src[0], f1 = src[1], f2 = src[2], f3 = src[3];
        float v[16] = {f0.x,f0.y,f0.z,f0.w, f1.x,f1.y,f1.z,f1.w,
                       f2.x,f2.y,f2.z,f2.w, f3.x,f3.y,f3.z,f3.w};
        v8bf o0, o1;
        #pragma unroll
        for (int i = 0; i < 8; ++i) { o0[i] = (__bf16)v[i]; o1[i] = (__bf16)v[8 + i]; }
        v8bf* dst = (v8bf*)(ws + OFF_ACSBF) + tid * 2;
        dst[0] = o0; dst[1] = o1;
        float best = v[0]; int bi = 0;
        #pragma unroll
        for (int c = 1; c < 16; ++c) if (v[c] > best) { best = v[c]; bi = c; }
        ((unsigned char*)(ws + OFF_AMX))[tid] = (unsigned char)bi;
        return;
    }
    tid -= N_ACSROW;
    if (tid < N_W1F) {             // W1 -> bf16 fragment-order [p][kc][nt][lane][8]; k==176 row = b1
        const int n4 = (int)(tid & 31) * 4;
        const int k  = (int)((tid >> 5) % 192);
        const int p  = (int)(tid / 6144);
        const float* W1; const float* B1;
        if (p < 12) { int ai = p / 3, hj = p % 3; int wi = hj * NA + ai;
                      W1 = eW1 + (size_t)wi * INsz * Dsz; B1 = eb1 + (size_t)wi * Dsz; }
        else { int qq = p - 12; int ai = qq >> 1, jj = qq & 1; int wi = jj * NA + ai;
               W1 = iW1 + (size_t)wi * INsz * Dsz; B1 = ib1 + (size_t)wi * Dsz; }
        float4 f;
        if (k < INsz)       f = *(const float4*)(W1 + (size_t)k * Dsz + n4);
        else if (k == INsz) f = *(const float4*)(B1 + n4);
        else                f = (float4){0.f, 0.f, 0.f, 0.f};
        const int kc = k >> 5, q = (k >> 3) & 3, j = k & 7;
        __bf16* dst = (__bf16*)(ws + OFF_W1F);
        const float fv[4] = {f.x, f.y, f.z, f.w};
        #pragma unroll
        for (int i = 0; i < 4; ++i) {
            const int n = n4 + i, nt = n >> 4, m = n & 15;
            dst[((size_t)(p * 6 + kc) * 8 + nt) * 512 + (q * 16 + m) * 8 + j] = (__bf16)fv[i];
        }
        return;
    }
    tid -= N_W1F;
    if (tid < N_ENCWF) {           // encW -> bf16 fragment-order [kc][nt][lane][8]
        const int n4 = (int)(tid & 31) * 4;
        const int k  = (int)(tid >> 5);
        float4 f = *(const float4*)(encW + (size_t)k * Dsz + n4);
        const int kc = k >> 5, q = (k >> 3) & 3, j = k & 7;
        __bf16* dst = (__bf16*)(ws + OFF_ENCWF);
        const float fv[4] = {f.x, f.y, f.z, f.w};
        #pragma unroll
        for (int i = 0; i < 4; ++i) {
            const int n = n4 + i, nt = n >> 4, m = n & 15;
            dst[((size_t)kc * 8 + nt) * 512 + (q * 16 + m) * 8 + j] = (__bf16)fv[i];
        }
        return;
    }
    tid -= N_ENCWF;
    if (tid < N_W2T) {             // W2 -> bf16 [p][c][(dlow^c)][dtile]  (d = dtile*16 + dlow)
        int d = (int)(tid & 127);
        int rest = (int)(tid >> 7);
        int c = rest & 15, p = rest >> 4;
        const float* W2;
        if (p < 12) { int ai = p / 3, hj = p % 3; W2 = eW2 + (size_t)(hj * NA + ai) * Dsz * Csz; }
        else { int qq = p - 12; int ai = qq >> 1, jj = qq & 1; W2 = iW2 + (size_t)(jj * NA + ai) * Dsz * Csz; }
        const int dlow = d & 15, dt = d >> 4;
        ((__bf16*)(ws + OFF_W2T))[(size_t)p * 2048 + c * 128 + ((dlow ^ c) * 8) + dt]
            = (__bf16)W2[(size_t)d * Csz + c];
        return;
    }
    tid -= N_W2T;
    if (tid < N_ZERO) {            // one-hot bias-row feed: bf16 {1.0, 0,0,...} then zeros
        ((unsigned int*)(ws + OFF_ZERO))[tid] = (tid == 0) ? 0x00003F80u : 0u;
    }
}

// ---------------- encoder: MFMA; epilogue via per-wave LDS transpose ----------------
// Output layout enc_t: byte = rt*4096 + s*256 + m*16 + j*2  holds enc[rt*16 + m][s*8 + j]
__global__ __launch_bounds__(256) void enc_kernel(const float* __restrict__ sv,
                                                  const float* __restrict__ encb,
                                                  char* __restrict__ ws)
{
    __shared__ __bf16 tb[4][16 * 136];   // per-wave 16 rows x 136 (pad for banks+align)

    const int t = threadIdx.x;
    const int wv = t >> 6, lane = t & 63, m = lane & 15, q = lane >> 4;
    const int R = blockIdx.x * 64 + wv * 16 + m;
    const __bf16* encwf = (const __bf16*)(ws + OFF_ENCWF);
    char* enct = ws + OFF_ENC;

    v4f acc[8];
    #pragma unroll
    for (int nt = 0; nt < 8; ++nt) acc[nt] = (v4f){0.f, 0.f, 0.f, 0.f};

    const float* arow = sv + (size_t)R * Ssz + q * 8;
    #pragma unroll
    for (int kc = 0; kc < 8; ++kc) {
        float4 f0 = *(const float4*)(arow + kc * 32);
        float4 f1 = *(const float4*)(arow + kc * 32 + 4);
        v8bf af;
        af[0]=(__bf16)f0.x; af[1]=(__bf16)f0.y; af[2]=(__bf16)f0.z; af[3]=(__bf16)f0.w;
        af[4]=(__bf16)f1.x; af[5]=(__bf16)f1.y; af[6]=(__bf16)f1.z; af[7]=(__bf16)f1.w;
        #pragma unroll
        for (int nt = 0; nt < 8; ++nt) {
            v8bf bf = *(const v8bf*)(encwf + ((size_t)kc * 8 + nt) * 512 + lane * 8);
            acc[nt] = __builtin_amdgcn_mfma_f32_16x16x32_bf16(af, bf, acc[nt], 0, 0, 0);
        }
    }
    #pragma unroll
    for (int nt = 0; nt < 8; ++nt) {
        const float bias = encb[nt * 16 + m];
        #pragma unroll
        for (int rg = 0; rg < 4; ++rg) {
            float v = acc[nt][rg] + bias;
            v = v > 0.f ? v : 0.f;
            tb[wv][(q * 4 + rg) * 136 + nt * 16 + m] = (__bf16)v;
        }
    }
    __syncthreads();
    const int rt = blockIdx.x * 4 + wv;
    #pragma unroll
    for (int kc = 0; kc < 4; ++kc) {
        v8bf v = *(const v8bf*)&tb[wv][m * 136 + kc * 32 + q * 8];
        *(v8bf*)(enct + ((size_t)(rt * 4 + kc) * 64 + lane) * 16) = v;
    }
}

// ---------------- critic: swapped mfma, 2-KC-deep triple-buffered X prefetch, slim epilogue ----------------
#define LD_AF(D, KC, GG) \
  { _Pragma("unroll") \
    for (int mt_ = 0; mt_ < 4; ++mt_) \
      D[mt_] = *(const v8bf*)(base[KC] + (size_t)((mt_ + 16 * (GG)) * strd[KC])); }

// swapped operand order: A = W1 fragment (from LDS), B = X fragment (per-lane rows)
#define MFMA_KC(AF, KC) \
  { _Pragma("unroll") \
    for (int nt_ = 0; nt_ < 8; ++nt_) { \
      v8bf bf_ = *(const v8bf*)&w1s[(size_t)(((KC) * 8 + nt_) * 512) + lane * 8]; \
      acc[0][nt_] = __builtin_amdgcn_mfma_f32_16x16x32_bf16(bf_, AF[0], acc[0][nt_], 0, 0, 0); \
      acc[1][nt_] = __builtin_amdgcn_mfma_f32_16x16x32_bf16(bf_, AF[1], acc[1][nt_], 0, 0, 0); \
      acc[2][nt_] = __builtin_amdgcn_mfma_f32_16x16x32_bf16(bf_, AF[2], acc[2][nt_], 0, 0, 0); \
      acc[3][nt_] = __builtin_amdgcn_mfma_f32_16x16x32_bf16(bf_, AF[3], acc[3][nt_], 0, 0, 0); \
    } }

__global__ __launch_bounds__(256, 2) void critic_kernel(
    const float* __restrict__ eb2, const float* __restrict__ ib2,
    const char* __restrict__ ws, float* __restrict__ out)
{
    __shared__ __bf16 w1s[6 * 8 * 512];   // 48 KB B-panel (incl. bias row k=176), fragment order
    __shared__ __bf16 w2s[16 * 128];      // 4 KB W2 [c][(dlow^c)][dtile]

    const int t = threadIdx.x;
    const int p  = blockIdx.y;
    const int rb = blockIdx.x;
    const int wv = t >> 6, lane = t & 63, m = lane & 15, q = lane >> 4;

    int ai, hj;
    const float* b2;
    float* outp;
    if (p < 12) {
        ai = p / 3; hj = p % 3;
        b2 = eb2 + (size_t)(hj * NA + ai) * Csz;
        outp = out + (size_t)(ai * NH + hj) * Bsz;
    } else {
        const int qq = p - 12; ai = qq >> 1; const int jj = qq & 1; hj = jj + 1;
        b2 = ib2 + (size_t)(jj * NA + ai) * Csz;
        outp = out + (size_t)NA * NH * Bsz + (size_t)(ai * NHI + jj) * Bsz;
    }

    const char* acsb = ws + OFF_ACSBF;
    const char* enct = ws + OFF_ENC;
    const __bf16* w1f = (const __bf16*)(ws + OFF_W1F) + (size_t)p * 6 * 8 * 512;
    const __bf16* w2t = (const __bf16*)(ws + OFF_W2T) + (size_t)p * 2048;
    const unsigned char* amxp = (const unsigned char*)(ws + OFF_AMX)
        + (size_t)(ai * NH + hj) * Bsz + (size_t)rb * 512 + wv * 64;
    const char* zerop = ws + OFF_ZERO;

    // stage W1 panel (48 KB) + W2 (4 KB) into LDS (layouts already baked, linear copies)
    {
        const v8bf* src = (const v8bf*)w1f;
        #pragma unroll
        for (int i = 0; i < 12; ++i)
            ((v8bf*)w1s)[i * 256 + t] = src[i * 256 + t];
        ((v8bf*)w2s)[t] = ((const v8bf*)w2t)[t];
    }

    // per-lane X-fragment base pointers; stride = bytes per 16-row (mt) step
    const int loo0 = 0 + (0 >= ai), loo1 = 1 + (1 >= ai), loo2 = 2 + (2 >= ai);
    const size_t rowoff = ((size_t)rb * 512 + wv * 64 + m) * 32;
    const char* pl0 = acsb + (size_t)(loo0 * NH + hj) * Bsz * 32 + rowoff;
    const char* pl1 = acsb + (size_t)(loo1 * NH + hj) * Bsz * 32 + rowoff;
    const char* pl2 = acsb + (size_t)(loo2 * NH + hj) * Bsz * 32 + rowoff;
    const int rt0 = rb * 32 + wv * 4;
    const char* encB = enct + (size_t)rt0 * 4096 + m * 16;

    const char* base[6];
    int strd[6];
    base[0] = (q < 2) ? (pl0 + q * 16) : (pl1 + (q - 2) * 16);           strd[0] = 512;
    base[1] = (q < 2) ? (pl2 + q * 16) : (encB + (q - 2) * 256);         strd[1] = (q < 2) ? 512 : 4096;
    base[2] = encB + (q + 2)  * 256;                                     strd[2] = 4096;
    base[3] = encB + (q + 6)  * 256;                                     strd[3] = 4096;
    base[4] = encB + (q + 10) * 256;                                     strd[4] = 4096;
    base[5] = (q < 2) ? (encB + (14 + q) * 256) : (zerop + (q - 2) * 16);
    strd[5] = (q < 2) ? 4096 : 0;    // q==2 reads {1,0,..} -> bias row; q==3 reads zeros

    v4f acc[4][8];
    #pragma unroll
    for (int i = 0; i < 4; ++i)
        #pragma unroll
        for (int j = 0; j < 8; ++j)
            acc[i][j] = (v4f){0.f, 0.f, 0.f, 0.f};

    // triple-buffered X fragments: always 2 KCs in flight
    v8bf af0[4], af1[4], af2[4];
    LD_AF(af0, 0, 0)
    LD_AF(af1, 1, 0)

    __syncthreads();

    #pragma unroll
    for (int g = 0; g < GT; ++g) {
        // prefetch this g's argmax bytes (short-lived scalars, needed at epilogue)
        int cb[4];
        #pragma unroll
        for (int mt = 0; mt < 4; ++mt)
            cb[mt] = amxp[g * 256 + mt * 16 + m];

        LD_AF(af2, 2, g)  MFMA_KC(af0, 0)
        LD_AF(af0, 3, g)  MFMA_KC(af1, 1)
        LD_AF(af1, 4, g)  MFMA_KC(af2, 2)
        LD_AF(af2, 5, g)  MFMA_KC(af0, 3)
        if (g + 1 < GT) { LD_AF(af0, 0, g + 1) }
        MFMA_KC(af1, 4)
        if (g + 1 < GT) { LD_AF(af1, 1, g + 1) }
        MFMA_KC(af2, 5)

        // epilogue: lane holds z[d = nt*16 + q*4 + rg] of row (mt*16 + m); bias folded in GEMM.
        // sequential rg-pairs -> at most 2 W2 vectors live (register-pressure cap, no spill)
        #pragma unroll
        for (int mt = 0; mt < 4; ++mt) {
            const int c = cb[mt];
            const __bf16* wcb = &w2s[c * 128];
            float s0 = 0.f, s1 = 0.f;
            #pragma unroll
            for (int rg = 0; rg < 4; rg += 2) {
                const v8bf wa = *(const v8bf*)&wcb[((q * 4 + rg) ^ c) * 8];
                const v8bf wb = *(const v8bf*)&wcb[((q * 4 + rg + 1) ^ c) * 8];
                #pragma unroll
                for (int nt = 0; nt < 8; ++nt) {
                    s0 += fmaxf(acc[mt][nt][rg],     0.f) * (float)wa[nt];
                    s1 += fmaxf(acc[mt][nt][rg + 1], 0.f) * (float)wb[nt];
                }
            }
            float tsum = s0 + s1;
            tsum += __shfl_xor(tsum, 16, 64);
            tsum += __shfl_xor(tsum, 32, 64);
            if (q == 0)
                outp[(size_t)rb * 512 + g * 256 + wv * 64 + mt * 16 + m] = tsum + b2[c];
            if (g + 1 < GT) {
                #pragma unroll
                for (int nt = 0; nt < 8; ++nt) acc[mt][nt] = (v4f){0.f, 0.f, 0.f, 0.f};
            }
        }
    }
}

extern "C" void kernel_launch(void* const* d_in, const int* in_sizes, int n_in,
                              void* d_out, int out_size, void* d_ws, size_t ws_size,
                              hipStream_t stream) {
    const float* sv   = (const float*)d_in[0];
    const float* acs  = (const float*)d_in[1];
    const float* encW = (const float*)d_in[2];
    const float* encb = (const float*)d_in[3];
    const float* eW1  = (const float*)d_in[4];
    const float* eb1  = (const float*)d_in[5];
    const float* eW2  = (const float*)d_in[6];
    const float* eb2  = (const float*)d_in[7];
    const float* iW1  = (const float*)d_in[8];
    const float* ib1  = (const float*)d_in[9];
    const float* iW2  = (const float*)d_in[10];
    const float* ib2  = (const float*)d_in[11];
    float* out = (float*)d_out;
    char* ws = (char*)d_ws;

    hipLaunchKernelGGL(prep_kernel, dim3((N_PREP + 255) / 256), dim3(256), 0, stream,
                       acs, encW, eW1, iW1, eW2, iW2, eb1, ib1, ws);
    hipLaunchKernelGGL(enc_kernel, dim3(Bsz / 64), dim3(256), 0, stream, sv, encb, ws);
    hipLaunchKernelGGL(critic_kernel, dim3(Bsz / 512, NP), dim3(256), 0, stream,
                       eb2, ib2, ws, out);
}

// Round 4
// 153.095 us; speedup vs baseline: 1.1558x; 1.0583x over previous
//
#include <hip/hip_runtime.h>

#define NA 4
#define NH 3
#define NHI 2
#define Bsz 32768
#define Ssz 256
#define Csz 16
#define Dsz 128
#define INsz 176
#define NP 20
#define KP 192
#define GT 2

typedef __bf16 v8bf __attribute__((ext_vector_type(8)));
typedef float v4f __attribute__((ext_vector_type(4)));

// ---- ws layout (bytes) ----
// X column order is REORDERED to [enc(0..127) | acs-LOO(128..175) | bias(176) | 0(177..191)],
// baked into the W1F permutation below.
#define OFF_ENC    0                    // enc_t tiled: [rt=B/16][16 chunks][lane][8bf16] = 8388608
#define OFF_ACSBF  8388608              // acs_t tiled: [plane 12][rt 2048][32][8bf16] = 12582912 (1 MiB/plane)
#define OFF_W1F    20971520             // NP*6*8*512*2       = 983040  (fragment-order, new col order)
#define OFF_ENCWF  21954560             // 8*8*512*2          = 65536   (fragment-order)
#define OFF_W2T    22020096             // NP*2048*2 bf16, layout [p][c][(dlow^c)][dtile]
#define OFF_AMX    22102016             // NA*NH*Bsz          = 393216
#define OFF_ZERO   22495232             // 64 B: bf16 {1.0, 0...} then zeros (bias one-hot + zero pad)

// ---- prep ranges ----
#define N_ACSROW (NA*NH*Bsz)            // 393216
#define N_W1F   (NP*192*32)             // 122880
#define N_ENCWF (256*32)                // 8192
#define N_W2T   (NP*Csz*Dsz)            // 40960
#define N_ZERO  16
#define N_PREP  (N_ACSROW+N_W1F+N_ENCWF+N_W2T+N_ZERO)

__global__ __launch_bounds__(256) void prep_kernel(
    const float* __restrict__ acs, const float* __restrict__ encW,
    const float* __restrict__ eW1, const float* __restrict__ iW1,
    const float* __restrict__ eW2, const float* __restrict__ iW2,
    const float* __restrict__ eb1, const float* __restrict__ ib1,
    char* __restrict__ ws)
{
    long tid = (long)blockIdx.x * 256 + threadIdx.x;

    if (tid < N_ACSROW) {          // acs row: fp32->bf16 + argmax; store TILED [plane][rt][qh*16+m][8]
        const float4* src = (const float4*)(acs + (size_t)tid * 16);
        float4 f0 = src[0], f1 = src[1], f2 = src[2], f3 = src[3];
        float v[16] = {f0.x,f0.y,f0.z,f0.w, f1.x,f1.y,f1.z,f1.w,
                       f2.x,f2.y,f2.z,f2.w, f3.x,f3.y,f3.z,f3.w};
        v8bf o0, o1;
        #pragma unroll
        for (int i = 0; i < 8; ++i) { o0[i] = (__bf16)v[i]; o1[i] = (__bf16)v[8 + i]; }
        const int plane = (int)(tid >> 15);          // tid / Bsz
        const int b     = (int)(tid & 32767);
        const int rt    = b >> 4, mm = b & 15;
        char* dstb = ws + OFF_ACSBF + (size_t)plane * 1048576 + (size_t)rt * 512 + mm * 16;
        *(v8bf*)dstb         = o0;                   // cols 0..7  (chunk 0)
        *(v8bf*)(dstb + 256) = o1;                   // cols 8..15 (chunk 1)
        float best = v[0]; int bi = 0;
        #pragma unroll
        for (int c = 1; c < 16; ++c) if (v[c] > best) { best = v[c]; bi = c; }
        ((unsigned char*)(ws + OFF_AMX))[tid] = (unsigned char)bi;
        return;
    }
    tid -= N_ACSROW;
    if (tid < N_W1F) {             // W1 -> bf16 fragment-order [p][kc][nt][lane][8], REORDERED cols:
        const int n4 = (int)(tid & 31) * 4;          // k'<128: enc (src row 48+k'); 128..175: acs (k'-128);
        const int k  = (int)((tid >> 5) % 192);      // 176: b1; else 0
        const int p  = (int)(tid / 6144);
        const float* W1; const float* B1;
        if (p < 12) { int ai = p / 3, hj = p % 3; int wi = hj * NA + ai;
                      W1 = eW1 + (size_t)wi * INsz * Dsz; B1 = eb1 + (size_t)wi * Dsz; }
        else { int qq = p - 12; int ai = qq >> 1, jj = qq & 1; int wi = jj * NA + ai;
               W1 = iW1 + (size_t)wi * INsz * Dsz; B1 = ib1 + (size_t)wi * Dsz; }
        float4 f;
        if (k < 128)        f = *(const float4*)(W1 + (size_t)(48 + k) * Dsz + n4);
        else if (k < INsz)  f = *(const float4*)(W1 + (size_t)(k - 128) * Dsz + n4);
        else if (k == INsz) f = *(const float4*)(B1 + n4);
        else                f = (float4){0.f, 0.f, 0.f, 0.f};
        const int kc = k >> 5, q = (k >> 3) & 3, j = k & 7;
        __bf16* dst = (__bf16*)(ws + OFF_W1F);
        const float fv[4] = {f.x, f.y, f.z, f.w};
        #pragma unroll
        for (int i = 0; i < 4; ++i) {
            const int n = n4 + i, nt = n >> 4, m = n & 15;
            dst[((size_t)(p * 6 + kc) * 8 + nt) * 512 + (q * 16 + m) * 8 + j] = (__bf16)fv[i];
        }
        return;
    }
    tid -= N_W1F;
    if (tid < N_ENCWF) {           // encW -> bf16 fragment-order [kc][nt][lane][8] (enc GEMM B, unchanged)
        const int n4 = (int)(tid & 31) * 4;
        const int k  = (int)(tid >> 5);
        float4 f = *(const float4*)(encW + (size_t)k * Dsz + n4);
        const int kc = k >> 5, q = (k >> 3) & 3, j = k & 7;
        __bf16* dst = (__bf16*)(ws + OFF_ENCWF);
        const float fv[4] = {f.x, f.y, f.z, f.w};
        #pragma unroll
        for (int i = 0; i < 4; ++i) {
            const int n = n4 + i, nt = n >> 4, m = n & 15;
            dst[((size_t)kc * 8 + nt) * 512 + (q * 16 + m) * 8 + j] = (__bf16)fv[i];
        }
        return;
    }
    tid -= N_ENCWF;
    if (tid < N_W2T) {             // W2 -> bf16 [p][c][(dlow^c)][dtile]  (d = dtile*16 + dlow)
        int d = (int)(tid & 127);
        int rest = (int)(tid >> 7);
        int c = rest & 15, p = rest >> 4;
        const float* W2;
        if (p < 12) { int ai = p / 3, hj = p % 3; W2 = eW2 + (size_t)(hj * NA + ai) * Dsz * Csz; }
        else { int qq = p - 12; int ai = qq >> 1, jj = qq & 1; W2 = iW2 + (size_t)(jj * NA + ai) * Dsz * Csz; }
        const int dlow = d & 15, dt = d >> 4;
        ((__bf16*)(ws + OFF_W2T))[(size_t)p * 2048 + c * 128 + ((dlow ^ c) * 8) + dt]
            = (__bf16)W2[(size_t)d * Csz + c];
        return;
    }
    tid -= N_W2T;
    if (tid < N_ZERO) {            // bias one-hot: bytes 0..15 = {1.0bf16,0...}, 16..63 = 0
        ((unsigned int*)(ws + OFF_ZERO))[tid] = (tid == 0) ? 0x00003F80u : 0u;
    }
}

// ---------------- encoder: MFMA; epilogue via per-wave LDS transpose ----------------
// Output layout enc_t: byte = rt*4096 + s*256 + m*16 + j*2  holds enc[rt*16 + m][s*8 + j]
// Critic fragment for (rt, kc, lane=(q,m)) is at rt*4096 + kc*1024 + lane*16 (wave-contiguous 1KB).
__global__ __launch_bounds__(256) void enc_kernel(const float* __restrict__ sv,
                                                  const float* __restrict__ encb,
                                                  char* __restrict__ ws)
{
    __shared__ __bf16 tb[4][16 * 136];   // per-wave 16 rows x 136 (pad for banks+align)

    const int t = threadIdx.x;
    const int wv = t >> 6, lane = t & 63, m = lane & 15, q = lane >> 4;
    const int R = blockIdx.x * 64 + wv * 16 + m;
    const __bf16* encwf = (const __bf16*)(ws + OFF_ENCWF);
    char* enct = ws + OFF_ENC;

    v4f acc[8];
    #pragma unroll
    for (int nt = 0; nt < 8; ++nt) acc[nt] = (v4f){0.f, 0.f, 0.f, 0.f};

    const float* arow = sv + (size_t)R * Ssz + q * 8;
    #pragma unroll
    for (int kc = 0; kc < 8; ++kc) {
        float4 f0 = *(const float4*)(arow + kc * 32);
        float4 f1 = *(const float4*)(arow + kc * 32 + 4);
        v8bf af;
        af[0]=(__bf16)f0.x; af[1]=(__bf16)f0.y; af[2]=(__bf16)f0.z; af[3]=(__bf16)f0.w;
        af[4]=(__bf16)f1.x; af[5]=(__bf16)f1.y; af[6]=(__bf16)f1.z; af[7]=(__bf16)f1.w;
        #pragma unroll
        for (int nt = 0; nt < 8; ++nt) {
            v8bf bf = *(const v8bf*)(encwf + ((size_t)kc * 8 + nt) * 512 + lane * 8);
            acc[nt] = __builtin_amdgcn_mfma_f32_16x16x32_bf16(af, bf, acc[nt], 0, 0, 0);
        }
    }
    #pragma unroll
    for (int nt = 0; nt < 8; ++nt) {
        const float bias = encb[nt * 16 + m];
        #pragma unroll
        for (int rg = 0; rg < 4; ++rg) {
            float v = acc[nt][rg] + bias;
            v = v > 0.f ? v : 0.f;
            tb[wv][(q * 4 + rg) * 136 + nt * 16 + m] = (__bf16)v;
        }
    }
    __syncthreads();
    const int rt = blockIdx.x * 4 + wv;
    #pragma unroll
    for (int kc = 0; kc < 4; ++kc) {
        v8bf v = *(const v8bf*)&tb[wv][m * 136 + kc * 32 + q * 8];
        *(v8bf*)(enct + ((size_t)(rt * 4 + kc) * 64 + lane) * 16) = v;
    }
}

// ---------------- critic: reordered-K X gather (3 slim bases), swapped mfma, no spill ----------------
#define LD_E(D, KC, GG) \
  { _Pragma("unroll") \
    for (int mt_ = 0; mt_ < 4; ++mt_) \
      D[mt_] = *(const v8bf*)(encL + (GG) * 65536 + mt_ * 4096 + (KC) * 1024); }

#define LD_4(D, GG) \
  { _Pragma("unroll") \
    for (int mt_ = 0; mt_ < 4; ++mt_) \
      D[mt_] = *(const v8bf*)(a4L + (GG) * 8192 + mt_ * 512); }

#define LD_5(D, GG) \
  { _Pragma("unroll") \
    for (int mt_ = 0; mt_ < 4; ++mt_) \
      D[mt_] = *(const v8bf*)(a5L + (GG) * g5 + mt_ * s5); }

// swapped operand order: A = W1 fragment (from LDS), B = X fragment (per-lane rows)
#define MFMA_KC(AF, KC) \
  { _Pragma("unroll") \
    for (int nt_ = 0; nt_ < 8; ++nt_) { \
      v8bf bf_ = *(const v8bf*)&w1s[(size_t)(((KC) * 8 + nt_) * 512) + lane * 8]; \
      acc[0][nt_] = __builtin_amdgcn_mfma_f32_16x16x32_bf16(bf_, AF[0], acc[0][nt_], 0, 0, 0); \
      acc[1][nt_] = __builtin_amdgcn_mfma_f32_16x16x32_bf16(bf_, AF[1], acc[1][nt_], 0, 0, 0); \
      acc[2][nt_] = __builtin_amdgcn_mfma_f32_16x16x32_bf16(bf_, AF[2], acc[2][nt_], 0, 0, 0); \
      acc[3][nt_] = __builtin_amdgcn_mfma_f32_16x16x32_bf16(bf_, AF[3], acc[3][nt_], 0, 0, 0); \
    } }

__global__ __launch_bounds__(256, 2) void critic_kernel(
    const float* __restrict__ eb2, const float* __restrict__ ib2,
    const char* __restrict__ ws, float* __restrict__ out)
{
    __shared__ __bf16 w1s[6 * 8 * 512];   // 48 KB W1 panel (incl. bias row), fragment order
    __shared__ __bf16 w2s[16 * 128];      // 4 KB W2 [c][(dlow^c)][dtile]
    __shared__ float  b2s[16];

    const int t = threadIdx.x;
    const int p  = blockIdx.y;
    const int rb = blockIdx.x;
    const int wv = t >> 6, lane = t & 63, m = lane & 15, q = lane >> 4;

    int ai, hj;
    const float* b2;
    float* outp;
    if (p < 12) {
        ai = p / 3; hj = p % 3;
        b2 = eb2 + (size_t)(hj * NA + ai) * Csz;
        outp = out + (size_t)(ai * NH + hj) * Bsz;
    } else {
        const int qq = p - 12; ai = qq >> 1; const int jj = qq & 1; hj = jj + 1;
        b2 = ib2 + (size_t)(jj * NA + ai) * Csz;
        outp = out + (size_t)NA * NH * Bsz + (size_t)(ai * NHI + jj) * Bsz;
    }

    const __bf16* w1f = (const __bf16*)(ws + OFF_W1F) + (size_t)p * 6 * 8 * 512;
    const __bf16* w2t = (const __bf16*)(ws + OFF_W2T) + (size_t)p * 2048;
    const unsigned char* amxp = (const unsigned char*)(ws + OFF_AMX)
        + (size_t)(ai * NH + hj) * Bsz + (size_t)rb * 512 + wv * 64;

    // stage W1 panel (48 KB) + W2 (4 KB) + b2 into LDS
    {
        const v8bf* src = (const v8bf*)w1f;
        #pragma unroll
        for (int i = 0; i < 12; ++i)
            ((v8bf*)w1s)[i * 256 + t] = src[i * 256 + t];
        ((v8bf*)w2s)[t] = ((const v8bf*)w2t)[t];
        if (t < 16) b2s[t] = b2[t];
    }

    // slim per-lane X bases (tiled layouts -> base + immediate offsets)
    const int loo0 = 0 + (0 >= ai), loo1 = 1 + (1 >= ai), loo2 = 2 + (2 >= ai);
    const int pA = loo0 * NH + hj, pB = loo1 * NH + hj, pC = loo2 * NH + hj;
    const int rtb = rb * 32 + wv * 4;
    const char* encL = ws + OFF_ENC + (size_t)rtb * 4096 + lane * 16;
    const size_t rtoff = (size_t)rtb * 512 + (lane & 31) * 16;
    const char* a4L = ws + OFF_ACSBF + (size_t)((q < 2) ? pA : pB) * 1048576 + rtoff;
    const char* a5L; int s5, g5;
    if (q < 2) { a5L = ws + OFF_ACSBF + (size_t)pC * 1048576 + rtoff; s5 = 512; g5 = 8192; }
    else       { a5L = ws + OFF_ZERO + (q - 2) * 16;                  s5 = 0;   g5 = 0;    }

    v4f acc[4][8];
    #pragma unroll
    for (int i = 0; i < 4; ++i)
        #pragma unroll
        for (int j = 0; j < 8; ++j)
            acc[i][j] = (v4f){0.f, 0.f, 0.f, 0.f};

    // triple-buffered X fragments: always 2 KCs in flight
    v8bf af0[4], af1[4], af2[4];
    LD_E(af0, 0, 0)
    LD_E(af1, 1, 0)

    __syncthreads();

    #pragma unroll
    for (int g = 0; g < GT; ++g) {
        LD_E(af2, 2, g)  MFMA_KC(af0, 0)
        LD_E(af0, 3, g)  MFMA_KC(af1, 1)
        LD_4(af1, g)     MFMA_KC(af2, 2)
        LD_5(af2, g)     MFMA_KC(af0, 3)
        if (g + 1 < GT) { LD_E(af0, 0, g + 1) }
        MFMA_KC(af1, 4)
        if (g + 1 < GT) { LD_E(af1, 1, g + 1) }
        MFMA_KC(af2, 5)

        // epilogue: lane holds z[d = nt*16 + q*4 + rg] of row (mt*16 + m); bias folded in GEMM.
        int cb[4];
        #pragma unroll
        for (int mt = 0; mt < 4; ++mt)
            cb[mt] = amxp[g * 256 + mt * 16 + m];

        #pragma unroll
        for (int mt = 0; mt < 4; ++mt) {
            const int c = cb[mt];
            const __bf16* wcb = &w2s[c * 128];
            float s0 = 0.f, s1 = 0.f;
            #pragma unroll
            for (int rg = 0; rg < 4; rg += 2) {
                const v8bf wa = *(const v8bf*)&wcb[((q * 4 + rg) ^ c) * 8];
                const v8bf wb = *(const v8bf*)&wcb[((q * 4 + rg + 1) ^ c) * 8];
                #pragma unroll
                for (int nt = 0; nt < 8; ++nt) {
                    s0 += fmaxf(acc[mt][nt][rg],     0.f) * (float)wa[nt];
                    s1 += fmaxf(acc[mt][nt][rg + 1], 0.f) * (float)wb[nt];
                }
            }
            float tsum = s0 + s1;
            tsum += __shfl_xor(tsum, 16, 64);
            tsum += __shfl_xor(tsum, 32, 64);
            if (q == 0)
                outp[(size_t)rb * 512 + g * 256 + wv * 64 + mt * 16 + m] = tsum + b2s[c];
            if (g + 1 < GT) {
                #pragma unroll
                for (int nt = 0; nt < 8; ++nt) acc[mt][nt] = (v4f){0.f, 0.f, 0.f, 0.f};
            }
        }
    }
}

extern "C" void kernel_launch(void* const* d_in, const int* in_sizes, int n_in,
                              void* d_out, int out_size, void* d_ws, size_t ws_size,
                              hipStream_t stream) {
    const float* sv   = (const float*)d_in[0];
    const float* acs  = (const float*)d_in[1];
    const float* encW = (const float*)d_in[2];
    const float* encb = (const float*)d_in[3];
    const float* eW1  = (const float*)d_in[4];
    const float* eb1  = (const float*)d_in[5];
    const float* eW2  = (const float*)d_in[6];
    const float* eb2  = (const float*)d_in[7];
    const float* iW1  = (const float*)d_in[8];
    const float* ib1  = (const float*)d_in[9];
    const float* iW2  = (const float*)d_in[10];
    const float* ib2  = (const float*)d_in[11];
    float* out = (float*)d_out;
    char* ws = (char*)d_ws;

    hipLaunchKernelGGL(prep_kernel, dim3((N_PREP + 255) / 256), dim3(256), 0, stream,
                       acs, encW, eW1, iW1, eW2, iW2, eb1, ib1, ws);
    hipLaunchKernelGGL(enc_kernel, dim3(Bsz / 64), dim3(256), 0, stream, sv, encb, ws);
    hipLaunchKernelGGL(critic_kernel, dim3(Bsz / 512, NP), dim3(256), 0, stream,
                       eb2, ib2, ws, out);
}

// Round 5
// 147.718 us; speedup vs baseline: 1.1979x; 1.0364x over previous
//
#include <hip/hip_runtime.h>

#define NA 4
#define NH 3
#define NHI 2
#define Bsz 32768
#define Ssz 256
#define Csz 16
#define Dsz 128
#define INsz 176
#define NP 20
#define KP 192
#define GT 2

typedef __bf16 v8bf __attribute__((ext_vector_type(8)));
typedef float v4f __attribute__((ext_vector_type(4)));

// ---- ws layout (bytes) ----
// X column order is REORDERED to [enc(0..127) | acs-LOO(128..175) | bias(176) | 0(177..191)],
// baked into the W1F permutation below.
#define OFF_ENC    0                    // enc_t tiled: [rt=B/16][16 chunks][lane][8bf16] = 8388608
#define OFF_ACSBF  8388608              // acs_t tiled: [plane 12][rt 2048][32][8bf16] = 12582912 (1 MiB/plane)
#define OFF_W1F    20971520             // NP*6*8*512*2       = 983040  (fragment-order, new col order)
#define OFF_ENCWF  21954560             // 8*8*512*2          = 65536   (fragment-order)
#define OFF_W2T    22020096             // NP*2048*2 bf16, layout [p][c][(dlow^c)][dtile]
#define OFF_AMX    22102016             // NA*NH*Bsz          = 393216
#define OFF_ZERO   22495232             // 64 B: bf16 {1.0, 0...} then zeros (bias one-hot + zero pad)

// ---- prep ranges ----
#define N_ACSROW (NA*NH*Bsz)            // 393216
#define N_W1F   (NP*192*32)             // 122880
#define N_ENCWF (256*32)                // 8192
#define N_W2T   (NP*Csz*Dsz)            // 40960
#define N_ZERO  16
#define N_PREP  (N_ACSROW+N_W1F+N_ENCWF+N_W2T+N_ZERO)

__global__ __launch_bounds__(256) void prep_kernel(
    const float* __restrict__ acs, const float* __restrict__ encW,
    const float* __restrict__ eW1, const float* __restrict__ iW1,
    const float* __restrict__ eW2, const float* __restrict__ iW2,
    const float* __restrict__ eb1, const float* __restrict__ ib1,
    char* __restrict__ ws)
{
    long tid = (long)blockIdx.x * 256 + threadIdx.x;

    if (tid < N_ACSROW) {          // acs row: fp32->bf16 + argmax; store TILED [plane][rt][qh*16+m][8]
        const float4* src = (const float4*)(acs + (size_t)tid * 16);
        float4 f0 = src[0], f1 = src[1], f2 = src[2], f3 = src[3];
        float v[16] = {f0.x,f0.y,f0.z,f0.w, f1.x,f1.y,f1.z,f1.w,
                       f2.x,f2.y,f2.z,f2.w, f3.x,f3.y,f3.z,f3.w};
        v8bf o0, o1;
        #pragma unroll
        for (int i = 0; i < 8; ++i) { o0[i] = (__bf16)v[i]; o1[i] = (__bf16)v[8 + i]; }
        const int plane = (int)(tid >> 15);          // tid / Bsz
        const int b     = (int)(tid & 32767);
        const int rt    = b >> 4, mm = b & 15;
        char* dstb = ws + OFF_ACSBF + (size_t)plane * 1048576 + (size_t)rt * 512 + mm * 16;
        *(v8bf*)dstb         = o0;                   // cols 0..7  (chunk 0)
        *(v8bf*)(dstb + 256) = o1;                   // cols 8..15 (chunk 1)
        float best = v[0]; int bi = 0;
        #pragma unroll
        for (int c = 1; c < 16; ++c) if (v[c] > best) { best = v[c]; bi = c; }
        ((unsigned char*)(ws + OFF_AMX))[tid] = (unsigned char)bi;
        return;
    }
    tid -= N_ACSROW;
    if (tid < N_W1F) {             // W1 -> bf16 fragment-order [p][kc][nt][lane][8], REORDERED cols:
        const int n4 = (int)(tid & 31) * 4;          // k'<128: enc (src row 48+k'); 128..175: acs (k'-128);
        const int k  = (int)((tid >> 5) % 192);      // 176: b1; else 0
        const int p  = (int)(tid / 6144);
        const float* W1; const float* B1;
        if (p < 12) { int ai = p / 3, hj = p % 3; int wi = hj * NA + ai;
                      W1 = eW1 + (size_t)wi * INsz * Dsz; B1 = eb1 + (size_t)wi * Dsz; }
        else { int qq = p - 12; int ai = qq >> 1, jj = qq & 1; int wi = jj * NA + ai;
               W1 = iW1 + (size_t)wi * INsz * Dsz; B1 = ib1 + (size_t)wi * Dsz; }
        float4 f;
        if (k < 128)        f = *(const float4*)(W1 + (size_t)(48 + k) * Dsz + n4);
        else if (k < INsz)  f = *(const float4*)(W1 + (size_t)(k - 128) * Dsz + n4);
        else if (k == INsz) f = *(const float4*)(B1 + n4);
        else                f = (float4){0.f, 0.f, 0.f, 0.f};
        const int kc = k >> 5, q = (k >> 3) & 3, j = k & 7;
        __bf16* dst = (__bf16*)(ws + OFF_W1F);
        const float fv[4] = {f.x, f.y, f.z, f.w};
        #pragma unroll
        for (int i = 0; i < 4; ++i) {
            const int n = n4 + i, nt = n >> 4, m = n & 15;
            dst[((size_t)(p * 6 + kc) * 8 + nt) * 512 + (q * 16 + m) * 8 + j] = (__bf16)fv[i];
        }
        return;
    }
    tid -= N_W1F;
    if (tid < N_ENCWF) {           // encW -> bf16 fragment-order [kc][nt][lane][8] (enc GEMM B, unchanged)
        const int n4 = (int)(tid & 31) * 4;
        const int k  = (int)(tid >> 5);
        float4 f = *(const float4*)(encW + (size_t)k * Dsz + n4);
        const int kc = k >> 5, q = (k >> 3) & 3, j = k & 7;
        __bf16* dst = (__bf16*)(ws + OFF_ENCWF);
        const float fv[4] = {f.x, f.y, f.z, f.w};
        #pragma unroll
        for (int i = 0; i < 4; ++i) {
            const int n = n4 + i, nt = n >> 4, m = n & 15;
            dst[((size_t)kc * 8 + nt) * 512 + (q * 16 + m) * 8 + j] = (__bf16)fv[i];
        }
        return;
    }
    tid -= N_ENCWF;
    if (tid < N_W2T) {             // W2 -> bf16 [p][c][(dlow^c)][dtile]  (d = dtile*16 + dlow)
        int d = (int)(tid & 127);
        int rest = (int)(tid >> 7);
        int c = rest & 15, p = rest >> 4;
        const float* W2;
        if (p < 12) { int ai = p / 3, hj = p % 3; W2 = eW2 + (size_t)(hj * NA + ai) * Dsz * Csz; }
        else { int qq = p - 12; int ai = qq >> 1, jj = qq & 1; W2 = iW2 + (size_t)(jj * NA + ai) * Dsz * Csz; }
        const int dlow = d & 15, dt = d >> 4;
        ((__bf16*)(ws + OFF_W2T))[(size_t)p * 2048 + c * 128 + ((dlow ^ c) * 8) + dt]
            = (__bf16)W2[(size_t)d * Csz + c];
        return;
    }
    tid -= N_W2T;
    if (tid < N_ZERO) {            // bias one-hot: bytes 0..15 = {1.0bf16,0...}, 16..63 = 0
        ((unsigned int*)(ws + OFF_ZERO))[tid] = (tid == 0) ? 0x00003F80u : 0u;
    }
}

// ---------------- encoder: LDS-staged sv (coalesced HBM), MFMA, per-wave transpose ----------------
// Output layout enc_t: byte = rt*4096 + s*256 + m*16 + j*2  holds enc[rt*16 + m][s*8 + j]
// All LDS traffic is wave-local (svs rows and tb tile owned by the producing wave) -> no barriers.
__global__ __launch_bounds__(256) void enc_kernel(const float* __restrict__ sv,
                                                  const float* __restrict__ encb,
                                                  char* __restrict__ ws)
{
    __shared__ __bf16 svs[64][264];      // 33.8 KB: 64 rows x 256 cols (+8 pad), bf16
    __shared__ __bf16 tb[4][16 * 136];   // 17 KB: per-wave output transpose tile

    const int t = threadIdx.x;
    const int wv = t >> 6, lane = t & 63, m = lane & 15, q = lane >> 4;
    const __bf16* encwf = (const __bf16*)(ws + OFF_ENCWF);
    char* enct = ws + OFF_ENC;

    // stage this wave's 16 rows of sv: 1 KB contiguous per load, fp32->bf16 on the fly
    {
        const float* src = sv + ((size_t)blockIdx.x * 64 + wv * 16) * Ssz;
        #pragma unroll
        for (int i = 0; i < 16; ++i) {
            float4 f = *(const float4*)(src + i * Ssz + lane * 4);
            __bf16* d = &svs[wv * 16 + i][lane * 4];
            d[0] = (__bf16)f.x; d[1] = (__bf16)f.y; d[2] = (__bf16)f.z; d[3] = (__bf16)f.w;
        }
    }

    v4f acc[8];
    #pragma unroll
    for (int nt = 0; nt < 8; ++nt) acc[nt] = (v4f){0.f, 0.f, 0.f, 0.f};

    #pragma unroll
    for (int kc = 0; kc < 8; ++kc) {
        v8bf af = *(const v8bf*)&svs[wv * 16 + m][kc * 32 + q * 8];
        #pragma unroll
        for (int nt = 0; nt < 8; ++nt) {
            v8bf bf = *(const v8bf*)(encwf + ((size_t)kc * 8 + nt) * 512 + lane * 8);
            acc[nt] = __builtin_amdgcn_mfma_f32_16x16x32_bf16(af, bf, acc[nt], 0, 0, 0);
        }
    }
    // bias+relu, transpose via per-wave LDS tile (wave-local -> lgkmcnt only, no barrier)
    #pragma unroll
    for (int nt = 0; nt < 8; ++nt) {
        const float bias = encb[nt * 16 + m];
        #pragma unroll
        for (int rg = 0; rg < 4; ++rg) {
            float v = acc[nt][rg] + bias;
            v = v > 0.f ? v : 0.f;
            tb[wv][(q * 4 + rg) * 136 + nt * 16 + m] = (__bf16)v;
        }
    }
    const int rt = blockIdx.x * 4 + wv;
    #pragma unroll
    for (int kc = 0; kc < 4; ++kc) {
        v8bf v = *(const v8bf*)&tb[wv][m * 136 + kc * 32 + q * 8];
        *(v8bf*)(enct + ((size_t)(rt * 4 + kc) * 64 + lane) * 16) = v;
    }
}

// ---------------- critic: reordered-K X gather, swapped mfma, setprio'd MFMA clusters ----------------
#define LD_E(D, KC, GG) \
  { _Pragma("unroll") \
    for (int mt_ = 0; mt_ < 4; ++mt_) \
      D[mt_] = *(const v8bf*)(encL + (GG) * 65536 + mt_ * 4096 + (KC) * 1024); }

#define LD_4(D, GG) \
  { _Pragma("unroll") \
    for (int mt_ = 0; mt_ < 4; ++mt_) \
      D[mt_] = *(const v8bf*)(a4L + (GG) * 8192 + mt_ * 512); }

#define LD_5(D, GG) \
  { _Pragma("unroll") \
    for (int mt_ = 0; mt_ < 4; ++mt_) \
      D[mt_] = *(const v8bf*)(a5L + (GG) * g5 + mt_ * s5); }

// swapped operand order: A = W1 fragment (from LDS), B = X fragment (per-lane rows).
// setprio(1) keeps the MFMA wave favored while sibling waves run epilogue VALU (phase-diverse).
#define MFMA_KC(AF, KC) \
  { __builtin_amdgcn_s_setprio(1); \
    _Pragma("unroll") \
    for (int nt_ = 0; nt_ < 8; ++nt_) { \
      v8bf bf_ = *(const v8bf*)&w1s[(size_t)(((KC) * 8 + nt_) * 512) + lane * 8]; \
      acc[0][nt_] = __builtin_amdgcn_mfma_f32_16x16x32_bf16(bf_, AF[0], acc[0][nt_], 0, 0, 0); \
      acc[1][nt_] = __builtin_amdgcn_mfma_f32_16x16x32_bf16(bf_, AF[1], acc[1][nt_], 0, 0, 0); \
      acc[2][nt_] = __builtin_amdgcn_mfma_f32_16x16x32_bf16(bf_, AF[2], acc[2][nt_], 0, 0, 0); \
      acc[3][nt_] = __builtin_amdgcn_mfma_f32_16x16x32_bf16(bf_, AF[3], acc[3][nt_], 0, 0, 0); \
    } \
    __builtin_amdgcn_s_setprio(0); }

__global__ __launch_bounds__(256, 2) void critic_kernel(
    const float* __restrict__ eb2, const float* __restrict__ ib2,
    const char* __restrict__ ws, float* __restrict__ out)
{
    __shared__ __bf16 w1s[6 * 8 * 512];   // 48 KB W1 panel (incl. bias row), fragment order
    __shared__ __bf16 w2s[16 * 128];      // 4 KB W2 [c][(dlow^c)][dtile]
    __shared__ float  b2s[16];

    const int t = threadIdx.x;
    const int p  = blockIdx.y;
    const int rb = blockIdx.x;
    const int wv = t >> 6, lane = t & 63, m = lane & 15, q = lane >> 4;

    int ai, hj;
    const float* b2;
    float* outp;
    if (p < 12) {
        ai = p / 3; hj = p % 3;
        b2 = eb2 + (size_t)(hj * NA + ai) * Csz;
        outp = out + (size_t)(ai * NH + hj) * Bsz;
    } else {
        const int qq = p - 12; ai = qq >> 1; const int jj = qq & 1; hj = jj + 1;
        b2 = ib2 + (size_t)(jj * NA + ai) * Csz;
        outp = out + (size_t)NA * NH * Bsz + (size_t)(ai * NHI + jj) * Bsz;
    }

    const __bf16* w1f = (const __bf16*)(ws + OFF_W1F) + (size_t)p * 6 * 8 * 512;
    const __bf16* w2t = (const __bf16*)(ws + OFF_W2T) + (size_t)p * 2048;
    const unsigned char* amxp = (const unsigned char*)(ws + OFF_AMX)
        + (size_t)(ai * NH + hj) * Bsz + (size_t)rb * 512 + wv * 64;

    // stage W1 panel (48 KB) + W2 (4 KB) + b2 into LDS
    {
        const v8bf* src = (const v8bf*)w1f;
        #pragma unroll
        for (int i = 0; i < 12; ++i)
            ((v8bf*)w1s)[i * 256 + t] = src[i * 256 + t];
        ((v8bf*)w2s)[t] = ((const v8bf*)w2t)[t];
        if (t < 16) b2s[t] = b2[t];
    }

    // slim per-lane X bases (tiled layouts -> base + immediate offsets)
    const int loo0 = 0 + (0 >= ai), loo1 = 1 + (1 >= ai), loo2 = 2 + (2 >= ai);
    const int pA = loo0 * NH + hj, pB = loo1 * NH + hj, pC = loo2 * NH + hj;
    const int rtb = rb * 32 + wv * 4;
    const char* encL = ws + OFF_ENC + (size_t)rtb * 4096 + lane * 16;
    const size_t rtoff = (size_t)rtb * 512 + (lane & 31) * 16;
    const char* a4L = ws + OFF_ACSBF + (size_t)((q < 2) ? pA : pB) * 1048576 + rtoff;
    const char* a5L; int s5, g5;
    if (q < 2) { a5L = ws + OFF_ACSBF + (size_t)pC * 1048576 + rtoff; s5 = 512; g5 = 8192; }
    else       { a5L = ws + OFF_ZERO + (q - 2) * 16;                  s5 = 0;   g5 = 0;    }

    v4f acc[4][8];
    #pragma unroll
    for (int i = 0; i < 4; ++i)
        #pragma unroll
        for (int j = 0; j < 8; ++j)
            acc[i][j] = (v4f){0.f, 0.f, 0.f, 0.f};

    // triple-buffered X fragments: always 2 KCs in flight
    v8bf af0[4], af1[4], af2[4];
    LD_E(af0, 0, 0)
    LD_E(af1, 1, 0)

    __syncthreads();

    #pragma unroll
    for (int g = 0; g < GT; ++g) {
        LD_E(af2, 2, g)  MFMA_KC(af0, 0)
        LD_E(af0, 3, g)  MFMA_KC(af1, 1)
        LD_4(af1, g)     MFMA_KC(af2, 2)
        LD_5(af2, g)     MFMA_KC(af0, 3)
        if (g + 1 < GT) { LD_E(af0, 0, g + 1) }
        MFMA_KC(af1, 4)
        if (g + 1 < GT) { LD_E(af1, 1, g + 1) }
        MFMA_KC(af2, 5)

        // epilogue: lane holds z[d = nt*16 + q*4 + rg] of row (mt*16 + m); bias folded in GEMM.
        int cb[4];
        #pragma unroll
        for (int mt = 0; mt < 4; ++mt)
            cb[mt] = amxp[g * 256 + mt * 16 + m];

        #pragma unroll
        for (int mt = 0; mt < 4; ++mt) {
            const int c = cb[mt];
            const __bf16* wcb = &w2s[c * 128];
            float s0 = 0.f, s1 = 0.f;
            #pragma unroll
            for (int rg = 0; rg < 4; rg += 2) {
                const v8bf wa = *(const v8bf*)&wcb[((q * 4 + rg) ^ c) * 8];
                const v8bf wb = *(const v8bf*)&wcb[((q * 4 + rg + 1) ^ c) * 8];
                #pragma unroll
                for (int nt = 0; nt < 8; ++nt) {
                    s0 += fmaxf(acc[mt][nt][rg],     0.f) * (float)wa[nt];
                    s1 += fmaxf(acc[mt][nt][rg + 1], 0.f) * (float)wb[nt];
                }
            }
            float tsum = s0 + s1;
            tsum += __shfl_xor(tsum, 16, 64);
            tsum += __shfl_xor(tsum, 32, 64);
            if (q == 0)
                outp[(size_t)rb * 512 + g * 256 + wv * 64 + mt * 16 + m] = tsum + b2s[c];
            if (g + 1 < GT) {
                #pragma unroll
                for (int nt = 0; nt < 8; ++nt) acc[mt][nt] = (v4f){0.f, 0.f, 0.f, 0.f};
            }
        }
    }
}

extern "C" void kernel_launch(void* const* d_in, const int* in_sizes, int n_in,
                              void* d_out, int out_size, void* d_ws, size_t ws_size,
                              hipStream_t stream) {
    const float* sv   = (const float*)d_in[0];
    const float* acs  = (const float*)d_in[1];
    const float* encW = (const float*)d_in[2];
    const float* encb = (const float*)d_in[3];
    const float* eW1  = (const float*)d_in[4];
    const float* eb1  = (const float*)d_in[5];
    const float* eW2  = (const float*)d_in[6];
    const float* eb2  = (const float*)d_in[7];
    const float* iW1  = (const float*)d_in[8];
    const float* ib1  = (const float*)d_in[9];
    const float* iW2  = (const float*)d_in[10];
    const float* ib2  = (const float*)d_in[11];
    float* out = (float*)d_out;
    char* ws = (char*)d_ws;

    hipLaunchKernelGGL(prep_kernel, dim3((N_PREP + 255) / 256), dim3(256), 0, stream,
                       acs, encW, eW1, iW1, eW2, iW2, eb1, ib1, ws);
    hipLaunchKernelGGL(enc_kernel, dim3(Bsz / 64), dim3(256), 0, stream, sv, encb, ws);
    hipLaunchKernelGGL(critic_kernel, dim3(Bsz / 512, NP), dim3(256), 0, stream,
                       eb2, ib2, ws, out);
}